// Round 2
// baseline (156.149 us; speedup 1.0000x reference)
//
#include <hip/hip_runtime.h>

#define DIM 128
#define NCELL (DIM*DIM*DIM)      // 2097152
#define NTILE (NCELL/16)         // 131072 wave-tiles of 16 cells

typedef __attribute__((ext_vector_type(8))) short bf16x8;
typedef __attribute__((ext_vector_type(4))) float f32x4;
typedef __attribute__((ext_vector_type(2))) float f32x2;

static __device__ __forceinline__ unsigned short f2bf_rne(float f) {
    union { float f; unsigned int i; } c; c.f = f;
    unsigned int u = c.i;
    return (unsigned short)((u + 0x7fffu + ((u >> 16) & 1u)) >> 16);
}
static __device__ __forceinline__ float bf2f(unsigned short u) {
    union { unsigned int i; float f; } c; c.i = ((unsigned int)u) << 16;
    return c.f;
}
static __device__ __forceinline__ unsigned int fbits(float f) {
    union { float f; unsigned int i; } c; c.f = f; return c.i;
}

// grid 2048 x block 256 = 8192 waves; each wave does 16 tiles of 16 cells.
__global__ __launch_bounds__(256) void lattice_kernel(
    const float* __restrict__ states,  // (N,8) fp32
    const float* __restrict__ W1,      // (56,16) fp32
    const float* __restrict__ b1,      // (16)
    const float* __restrict__ W2,      // (16,8)
    const float* __restrict__ b2,      // (8)
    float* __restrict__ out)           // (N,8) fp32
{
    __shared__ float h_lds[4][16 * 20];   // per-wave h tile, stride 20 (16B-aligned rows)

    const int tid  = threadIdx.x;
    const int lane = tid & 63;
    const int wave = tid >> 6;
    const int col  = lane & 15;   // MFMA: A-row m / C-col n
    const int quad = lane >> 4;   // MFMA: k-block selector

    // ---- W1 B-fragments, split into bf16 hi + lo (once). B[k][n]: n=col, k=quad*8+j ----
    bf16x8 bh0, bl0, bh1, bl1;
#pragma unroll
    for (int j = 0; j < 8; ++j) {
        int k0 = quad * 8 + j;
        float w = W1[k0 * 16 + col];
        unsigned short hi = f2bf_rne(w);
        bh0[j] = (short)hi;
        bl0[j] = (short)f2bf_rne(w - bf2f(hi));

        int k1 = 32 + quad * 8 + j;
        float w2v = (k1 < 56) ? W1[k1 * 16 + col] : 0.0f;   // zero-pad K 56..63
        hi = f2bf_rne(w2v);
        bh1[j] = (short)hi;
        bl1[j] = (short)f2bf_rne(w2v - bf2f(hi));
    }
    const float b1f = b1[col];

    // ---- GEMM2 per-lane fp32 weights: lane -> cell (lane>>2), outputs s0,s0+1 ----
    const int cell_l = lane >> 2;
    const int s0 = (lane & 3) * 2;
    float w2a[16], w2b[16];
#pragma unroll
    for (int h = 0; h < 16; ++h) {
        w2a[h] = W2[h * 8 + s0];
        w2b[h] = W2[h * 8 + s0 + 1];
    }
    const float b2a = b2[s0];
    const float b2b = b2[s0 + 1];

    // ---- per-lane neighbor offsets ----
    // MFMA0 k-blocks: 0=own, 1=x-1, 2=x+1, 3=y-1 ; MFMA1: 4=y+1, 5=z-1, 6=z+1, quad3=pad
    const int dx0 = (quad == 1) ? -1 : (quad == 2) ? 1 : 0;
    const int dy0 = (quad == 3) ? -1 : 0;
    const int dy1 = (quad == 0) ? 1 : 0;
    const int dz1 = (quad == 1) ? -1 : (quad == 2) ? 1 : 0;

    const int nwaves = (gridDim.x * blockDim.x) >> 6;
    int t = (blockIdx.x * blockDim.x + tid) >> 6;

    for (; t < NTILE; t += nwaves) {
        const int x = ((t & 7) << 4) + col;
        const int y = (t >> 3) & 127;
        const int z = t >> 10;

        const int x0 = (x + dx0) & 127;
        const int y0 = (y + dy0) & 127;
        const int n0 = (z << 14) | (y0 << 7) | x0;

        const int y1 = (y + dy1) & 127;
        const int z1 = (z + dz1) & 127;
        const int n1 = (z1 << 14) | (y1 << 7) | x;

        // fp32 state blocks (32 B each), then RTZ-pack high halves via v_perm
        const float* p0 = states + (size_t)n0 * 8;
        const float* p1 = states + (size_t)n1 * 8;
        f32x4 sa = *(const f32x4*)p0;
        f32x4 sb = *(const f32x4*)(p0 + 4);
        f32x4 sc = *(const f32x4*)p1;
        f32x4 sd = *(const f32x4*)(p1 + 4);

        union { bf16x8 v; unsigned int u[4]; } a0, a1;
        a0.u[0] = __builtin_amdgcn_perm(fbits(sa[1]), fbits(sa[0]), 0x07060302u);
        a0.u[1] = __builtin_amdgcn_perm(fbits(sa[3]), fbits(sa[2]), 0x07060302u);
        a0.u[2] = __builtin_amdgcn_perm(fbits(sb[1]), fbits(sb[0]), 0x07060302u);
        a0.u[3] = __builtin_amdgcn_perm(fbits(sb[3]), fbits(sb[2]), 0x07060302u);
        a1.u[0] = __builtin_amdgcn_perm(fbits(sc[1]), fbits(sc[0]), 0x07060302u);
        a1.u[1] = __builtin_amdgcn_perm(fbits(sc[3]), fbits(sc[2]), 0x07060302u);
        a1.u[2] = __builtin_amdgcn_perm(fbits(sd[1]), fbits(sd[0]), 0x07060302u);
        a1.u[3] = __builtin_amdgcn_perm(fbits(sd[3]), fbits(sd[2]), 0x07060302u);

        f32x4 acc = {0.f, 0.f, 0.f, 0.f};
        acc = __builtin_amdgcn_mfma_f32_16x16x32_bf16(a0.v, bh0, acc, 0, 0, 0);
        acc = __builtin_amdgcn_mfma_f32_16x16x32_bf16(a0.v, bl0, acc, 0, 0, 0);
        acc = __builtin_amdgcn_mfma_f32_16x16x32_bf16(a1.v, bh1, acc, 0, 0, 0);
        acc = __builtin_amdgcn_mfma_f32_16x16x32_bf16(a1.v, bl1, acc, 0, 0, 0);

        // bias + tanh; C/D: row(cell)=quad*4+r, col(hidden)=col
        float* hw = &h_lds[wave][0];
#pragma unroll
        for (int r = 0; r < 4; ++r) {
            float v = acc[r] + b1f;
            float e = __expf(2.0f * v);
            float th = 1.0f - 2.0f * __builtin_amdgcn_rcpf(e + 1.0f);
            hw[(quad * 4 + r) * 20 + col] = th;
        }

        __builtin_amdgcn_wave_barrier();
        __asm__ __volatile__("" ::: "memory");

        // GEMM2 (fp32 VALU): lane -> cell_l, outputs s0,s0+1
        const float* hr = &h_lds[wave][cell_l * 20];
        f32x4 h0 = *(const f32x4*)(hr);
        f32x4 h1 = *(const f32x4*)(hr + 4);
        f32x4 h2 = *(const f32x4*)(hr + 8);
        f32x4 h3 = *(const f32x4*)(hr + 12);

        float oa = b2a, ob = b2b;
#pragma unroll
        for (int k = 0; k < 4; ++k) {
            oa += h0[k] * w2a[k];      ob += h0[k] * w2b[k];
            oa += h1[k] * w2a[4 + k];  ob += h1[k] * w2b[4 + k];
            oa += h2[k] * w2a[8 + k];  ob += h2[k] * w2b[8 + k];
            oa += h3[k] * w2a[12 + k]; ob += h3[k] * w2b[12 + k];
        }

        f32x2 o2 = {oa, ob};
        *(f32x2*)(out + (size_t)(t * 16 + cell_l) * 8 + s0) = o2;

        __builtin_amdgcn_wave_barrier();
        __asm__ __volatile__("" ::: "memory");
    }
}

extern "C" void kernel_launch(void* const* d_in, const int* in_sizes, int n_in,
                              void* d_out, int out_size, void* d_ws, size_t ws_size,
                              hipStream_t stream) {
    const float* states = (const float*)d_in[0];
    const float* W1     = (const float*)d_in[1];
    const float* b1     = (const float*)d_in[2];
    const float* W2     = (const float*)d_in[3];
    const float* b2     = (const float*)d_in[4];
    float* out          = (float*)d_out;

    dim3 grid(2048), block(256);
    hipLaunchKernelGGL(lattice_kernel, grid, block, 0, stream,
                       states, W1, b1, W2, b2, out);
}

// Round 3
// 149.234 us; speedup vs baseline: 1.0463x; 1.0463x over previous
//
#include <hip/hip_runtime.h>

#define DIM 128
#define NCELL (DIM*DIM*DIM)      // 2097152
#define NTILE (NCELL/16)         // 131072 tiles of 16 cells (one x-run)

typedef __attribute__((ext_vector_type(8))) short bf16x8;
typedef __attribute__((ext_vector_type(4))) float f32x4;

static __device__ __forceinline__ unsigned short f2bf_rne(float f) {
    union { float f; unsigned int i; } c; c.f = f;
    unsigned int u = c.i;
    return (unsigned short)((u + 0x7fffu + ((u >> 16) & 1u)) >> 16);
}
static __device__ __forceinline__ float bf2f(unsigned short u) {
    union { unsigned int i; float f; } c; c.i = ((unsigned int)u) << 16;
    return c.f;
}
static __device__ __forceinline__ unsigned int fbits(float f) {
    union { float f; unsigned int i; } c; c.f = f; return c.i;
}
// pack two fp32 into {bf16(lo), bf16(hi)} dword with RNE
static __device__ __forceinline__ unsigned int pack_bf16_rne(float lo, float hi) {
    unsigned int ul = fbits(lo), uh = fbits(hi);
    unsigned int tl = ul + 0x7fffu + ((ul >> 16) & 1u);
    unsigned int th = uh + 0x7fffu + ((uh >> 16) & 1u);
    return __builtin_amdgcn_perm(th, tl, 0x07060302u);  // {th.hi16, tl.hi16}
}

// grid 2048 x 256: 8192 waves x 16 consecutive tiles each = 131072 tiles.
// z-slab swizzle: blockIdx&7 -> slab of 16 z-planes (XCD L2 locality).
__global__ __launch_bounds__(256) void lattice_kernel(
    const float* __restrict__ states,  // (N,8) fp32
    const float* __restrict__ W1,      // (56,16)
    const float* __restrict__ b1,      // (16)
    const float* __restrict__ W2,      // (16,8)
    const float* __restrict__ b2,      // (8)
    float* __restrict__ out)           // (N,8)
{
    const int tid  = threadIdx.x;
    const int lane = tid & 63;
    const int wave = tid >> 6;
    const int col  = lane & 15;   // GEMM1: cell (B-col / D-col); GEMM2: cell
    const int quad = lane >> 4;   // k-block selector / D-row block

    // ---- GEMM1 A = W1^T, hi/lo bf16 split. A[m=hidden=col][k=quad*8+j] = W1[k][col] ----
    bf16x8 w1h0, w1l0, w1h1, w1l1;
#pragma unroll
    for (int j = 0; j < 8; ++j) {
        int k0 = quad * 8 + j;
        float w = W1[k0 * 16 + col];
        unsigned short hi = f2bf_rne(w);
        w1h0[j] = (short)hi;
        w1l0[j] = (short)f2bf_rne(w - bf2f(hi));

        int k1 = 32 + quad * 8 + j;
        float w2v = (k1 < 56) ? W1[k1 * 16 + col] : 0.0f;   // zero-pad K 56..63
        hi = f2bf_rne(w2v);
        w1h1[j] = (short)hi;
        w1l1[j] = (short)f2bf_rne(w2v - bf2f(hi));
    }
    // D1 row = hidden = quad*4+r -> bias init
    f32x4 b1v;
#pragma unroll
    for (int r = 0; r < 4; ++r) b1v[r] = b1[quad * 4 + r];

    // ---- GEMM2 A = W2' (sparse embed), hi/lo. A2[m=s=col][k=8q+j] = (j<4) ? W2[4q+j][col] : 0 ----
    bf16x8 w2h, w2l;
#pragma unroll
    for (int j = 0; j < 8; ++j) {
        float w = (j < 4 && col < 8) ? W2[(quad * 4 + j) * 8 + col] : 0.0f;
        unsigned short hi = f2bf_rne(w);
        w2h[j] = (short)hi;
        w2l[j] = (short)f2bf_rne(w - bf2f(hi));
    }
    f32x4 b2v;
#pragma unroll
    for (int r = 0; r < 4; ++r) b2v[r] = (quad < 2) ? b2[quad * 4 + r] : 0.0f;

    // ---- per-lane neighbor offsets ----
    // block0 k-quads: 0=own, 1=x-1, 2=x+1, 3=y-1 ; block1: 4=y+1, 5=z-1, 6=z+1, quad3=pad(own)
    const int dx0 = (quad == 1) ? -1 : (quad == 2) ? 1 : 0;
    const int dy0 = (quad == 3) ? -1 : 0;
    const int dy1 = (quad == 0) ? 1 : 0;
    const int dz1 = (quad == 1) ? -1 : (quad == 2) ? 1 : 0;

    // ---- tile assignment: slab = blockIdx&7 (16 z-planes), contiguous 16 tiles/wave ----
    const int slab = blockIdx.x & 7;
    const int bq   = blockIdx.x >> 3;                 // 0..255 within slab
    const int t0   = slab * 16384 + bq * 64 + wave * 16;

    auto load_tile = [&](int t, f32x4& r0, f32x4& r1, f32x4& r2, f32x4& r3) {
        const int x = ((t & 7) << 4) + col;
        const int y = (t >> 3) & 127;
        const int z = t >> 10;
        const int x0 = (x + dx0) & 127;
        const int y0 = (y + dy0) & 127;
        const int n0 = (z << 14) | (y0 << 7) | x0;
        const int y1 = (y + dy1) & 127;
        const int z1 = (z + dz1) & 127;
        const int n1 = (z1 << 14) | (y1 << 7) | x;
        const float* p0 = states + (size_t)n0 * 8;
        const float* p1 = states + (size_t)n1 * 8;
        r0 = *(const f32x4*)p0;
        r1 = *(const f32x4*)(p0 + 4);
        r2 = *(const f32x4*)p1;
        r3 = *(const f32x4*)(p1 + 4);
    };

    f32x4 c0, c1, c2, c3;
    load_tile(t0, c0, c1, c2, c3);

#pragma unroll
    for (int i = 0; i < 16; ++i) {
        f32x4 n0v, n1v, n2v, n3v;
        if (i < 15) load_tile(t0 + i + 1, n0v, n1v, n2v, n3v);   // prefetch depth 1

        // pack B fragments (RTZ via v_perm: fp32 high halves)
        union { bf16x8 v; unsigned int u[4]; } s0f, s1f;
        s0f.u[0] = __builtin_amdgcn_perm(fbits(c0[1]), fbits(c0[0]), 0x07060302u);
        s0f.u[1] = __builtin_amdgcn_perm(fbits(c0[3]), fbits(c0[2]), 0x07060302u);
        s0f.u[2] = __builtin_amdgcn_perm(fbits(c1[1]), fbits(c1[0]), 0x07060302u);
        s0f.u[3] = __builtin_amdgcn_perm(fbits(c1[3]), fbits(c1[2]), 0x07060302u);
        s1f.u[0] = __builtin_amdgcn_perm(fbits(c2[1]), fbits(c2[0]), 0x07060302u);
        s1f.u[1] = __builtin_amdgcn_perm(fbits(c2[3]), fbits(c2[2]), 0x07060302u);
        s1f.u[2] = __builtin_amdgcn_perm(fbits(c3[1]), fbits(c3[0]), 0x07060302u);
        s1f.u[3] = __builtin_amdgcn_perm(fbits(c3[3]), fbits(c3[2]), 0x07060302u);

        // GEMM1: D1[hidden][cell], bias in C
        f32x4 acc = b1v;
        acc = __builtin_amdgcn_mfma_f32_16x16x32_bf16(w1h0, s0f.v, acc, 0, 0, 0);
        acc = __builtin_amdgcn_mfma_f32_16x16x32_bf16(w1l0, s0f.v, acc, 0, 0, 0);
        acc = __builtin_amdgcn_mfma_f32_16x16x32_bf16(w1h1, s1f.v, acc, 0, 0, 0);
        acc = __builtin_amdgcn_mfma_f32_16x16x32_bf16(w1l1, s1f.v, acc, 0, 0, 0);

        // tanh -> h[4q+r][col], then bf16 RNE pack into B2 fragment (k=8q+j, j<4)
        float h0t, h1t, h2t, h3t;
        {
            float v, e;
            v = acc[0]; e = __expf(2.0f * v); h0t = 1.0f - 2.0f * __builtin_amdgcn_rcpf(e + 1.0f);
            v = acc[1]; e = __expf(2.0f * v); h1t = 1.0f - 2.0f * __builtin_amdgcn_rcpf(e + 1.0f);
            v = acc[2]; e = __expf(2.0f * v); h2t = 1.0f - 2.0f * __builtin_amdgcn_rcpf(e + 1.0f);
            v = acc[3]; e = __expf(2.0f * v); h3t = 1.0f - 2.0f * __builtin_amdgcn_rcpf(e + 1.0f);
        }
        union { bf16x8 v; unsigned int u[4]; } hf;
        hf.u[0] = pack_bf16_rne(h0t, h1t);
        hf.u[1] = pack_bf16_rne(h2t, h3t);
        hf.u[2] = 0u;
        hf.u[3] = 0u;

        // GEMM2: D2[s][cell] = W2'^ . h, bias in C
        f32x4 acc2 = b2v;
        acc2 = __builtin_amdgcn_mfma_f32_16x16x32_bf16(w2h, hf.v, acc2, 0, 0, 0);
        acc2 = __builtin_amdgcn_mfma_f32_16x16x32_bf16(w2l, hf.v, acc2, 0, 0, 0);

        // store: lane(quad<2,col) holds out[cell=col][s=4q..4q+3]
        if (quad < 2) {
            *(f32x4*)(out + (size_t)((t0 + i) * 16 + col) * 8 + quad * 4) = acc2;
        }

        if (i < 15) { c0 = n0v; c1 = n1v; c2 = n2v; c3 = n3v; }
    }
}

extern "C" void kernel_launch(void* const* d_in, const int* in_sizes, int n_in,
                              void* d_out, int out_size, void* d_ws, size_t ws_size,
                              hipStream_t stream) {
    const float* states = (const float*)d_in[0];
    const float* W1     = (const float*)d_in[1];
    const float* b1     = (const float*)d_in[2];
    const float* W2     = (const float*)d_in[3];
    const float* b2     = (const float*)d_in[4];
    float* out          = (float*)d_out;

    dim3 grid(2048), block(256);
    hipLaunchKernelGGL(lattice_kernel, grid, block, 0, stream,
                       states, W1, b1, W2, b2, out);
}

// Round 4
// 143.875 us; speedup vs baseline: 1.0853x; 1.0373x over previous
//
#include <hip/hip_runtime.h>

#define NTILE 131072   // 128^3 / 16 cells per tile

typedef __attribute__((ext_vector_type(8))) short bf16x8;
typedef __attribute__((ext_vector_type(4))) float f32x4;
typedef __attribute__((ext_vector_type(4))) unsigned int u32x4;

static __device__ __forceinline__ unsigned short f2bf_rne(float f) {
    union { float f; unsigned int i; } c; c.f = f;
    unsigned int u = c.i;
    return (unsigned short)((u + 0x7fffu + ((u >> 16) & 1u)) >> 16);
}
static __device__ __forceinline__ float bf2f(unsigned short u) {
    union { unsigned int i; float f; } c; c.i = ((unsigned int)u) << 16;
    return c.f;
}
static __device__ __forceinline__ unsigned int fbits(float f) {
    union { float f; unsigned int i; } c; c.f = f; return c.i;
}
static __device__ __forceinline__ unsigned int pack_bf16_rne(float lo, float hi) {
    unsigned int ul = fbits(lo), uh = fbits(hi);
    unsigned int tl = ul + 0x7fffu + ((ul >> 16) & 1u);
    unsigned int th = uh + 0x7fffu + ((uh >> 16) & 1u);
    return __builtin_amdgcn_perm(th, tl, 0x07060302u);
}

struct Frags {
    bf16x8 w1h0, w1l0, w1h1, w1l1, w2h, w2l;
    f32x4 b1v, b2v;
};

// A = W1^T (hi/lo bf16 split), A2 = W2 embed (hi/lo); see round-3 derivation.
static __device__ __forceinline__ void build_frags(
    const float* W1, const float* b1, const float* W2, const float* b2,
    int col, int quad, Frags& F)
{
#pragma unroll
    for (int j = 0; j < 8; ++j) {
        int k0 = quad * 8 + j;
        float w = W1[k0 * 16 + col];
        unsigned short hi = f2bf_rne(w);
        F.w1h0[j] = (short)hi;
        F.w1l0[j] = (short)f2bf_rne(w - bf2f(hi));

        int k1 = 32 + quad * 8 + j;
        float wv = (k1 < 56) ? W1[k1 * 16 + col] : 0.0f;
        hi = f2bf_rne(wv);
        F.w1h1[j] = (short)hi;
        F.w1l1[j] = (short)f2bf_rne(wv - bf2f(hi));

        float w2 = (j < 4 && col < 8) ? W2[(quad * 4 + j) * 8 + col] : 0.0f;
        hi = f2bf_rne(w2);
        F.w2h[j] = (short)hi;
        F.w2l[j] = (short)f2bf_rne(w2 - bf2f(hi));
    }
#pragma unroll
    for (int r = 0; r < 4; ++r) {
        F.b1v[r] = b1[quad * 4 + r];
        F.b2v[r] = (quad < 2) ? b2[quad * 4 + r] : 0.0f;
    }
}

__global__ __launch_bounds__(64) void setup_kernel(
    const float* __restrict__ W1, const float* __restrict__ b1,
    const float* __restrict__ W2, const float* __restrict__ b2,
    u32x4* __restrict__ ws)
{
    const int lane = threadIdx.x;
    Frags F;
    build_frags(W1, b1, W2, b2, lane & 15, lane >> 4, F);
    union { bf16x8 v; u32x4 u; } c;
    c.v = F.w1h0; ws[0 * 64 + lane] = c.u;
    c.v = F.w1l0; ws[1 * 64 + lane] = c.u;
    c.v = F.w1h1; ws[2 * 64 + lane] = c.u;
    c.v = F.w1l1; ws[3 * 64 + lane] = c.u;
    c.v = F.w2h;  ws[4 * 64 + lane] = c.u;
    c.v = F.w2l;  ws[5 * 64 + lane] = c.u;
    union { f32x4 v; u32x4 u; } b;
    b.v = F.b1v; ws[6 * 64 + lane] = b.u;
    b.v = F.b2v; ws[7 * 64 + lane] = b.u;
}

// grid 8192 x 256 = 32768 waves; each wave: 4 consecutive tiles (one group),
// ALL 16 loads issued up front (MLP=16), then compute, then retire (wave churn).
template<bool USE_WS>
__global__ __launch_bounds__(256) void lattice_kernel(
    const float* __restrict__ states,
    const float* __restrict__ W1, const float* __restrict__ b1,
    const float* __restrict__ W2, const float* __restrict__ b2,
    float* __restrict__ out, const u32x4* __restrict__ ws)
{
    const int tid  = threadIdx.x;
    const int lane = tid & 63;
    const int wave = tid >> 6;
    const int col  = lane & 15;
    const int quad = lane >> 4;

    Frags F;
    if (USE_WS) {
        union { u32x4 u; bf16x8 v; } c;
        c.u = ws[0 * 64 + lane]; F.w1h0 = c.v;
        c.u = ws[1 * 64 + lane]; F.w1l0 = c.v;
        c.u = ws[2 * 64 + lane]; F.w1h1 = c.v;
        c.u = ws[3 * 64 + lane]; F.w1l1 = c.v;
        c.u = ws[4 * 64 + lane]; F.w2h  = c.v;
        c.u = ws[5 * 64 + lane]; F.w2l  = c.v;
        union { u32x4 u; f32x4 v; } b;
        b.u = ws[6 * 64 + lane]; F.b1v = b.v;
        b.u = ws[7 * 64 + lane]; F.b2v = b.v;
    } else {
        build_frags(W1, b1, W2, b2, col, quad, F);
    }

    // block0 k-quads: 0=own, 1=x-1, 2=x+1, 3=y-1 ; block1: 0=y+1, 1=z-1, 2=z+1,
    // 3=pad (zero weights) -> alias q0's y+1 addresses so TCP dedups its lines.
    const int dx0 = (quad == 1) ? -1 : (quad == 2) ? 1 : 0;
    const int dy0 = (quad == 3) ? -1 : 0;
    const int dy1 = (quad == 0 || quad == 3) ? 1 : 0;
    const int dz1 = (quad == 1) ? -1 : (quad == 2) ? 1 : 0;

    // z-slab swizzle: blockIdx&7 -> slab of 16 z-planes (XCD L2 locality)
    const int slab = blockIdx.x & 7;
    const int bq   = blockIdx.x >> 3;      // 0..1023 within slab
    const int t0   = slab * 16384 + bq * 16 + wave * 4;

    // ---- issue all 16 loads up front ----
    f32x4 d0[4], d1[4], d2[4], d3[4];
#pragma unroll
    for (int j = 0; j < 4; ++j) {
        const int t = t0 + j;
        const int x = ((t & 7) << 4) + col;
        const int y = (t >> 3) & 127;
        const int z = t >> 10;
        const int x0 = (x + dx0) & 127;
        const int y0 = (y + dy0) & 127;
        const int n0 = (z << 14) | (y0 << 7) | x0;
        const int y1 = (y + dy1) & 127;
        const int z1 = (z + dz1) & 127;
        const int n1 = (z1 << 14) | (y1 << 7) | x;
        const float* p0 = states + (size_t)n0 * 8;
        const float* p1 = states + (size_t)n1 * 8;
        d0[j] = *(const f32x4*)p0;
        d1[j] = *(const f32x4*)(p0 + 4);
        d2[j] = *(const f32x4*)p1;
        d3[j] = *(const f32x4*)(p1 + 4);
    }

    // ---- compute 4 tiles ----
#pragma unroll
    for (int j = 0; j < 4; ++j) {
        union { bf16x8 v; unsigned int u[4]; } s0f, s1f;
        s0f.u[0] = __builtin_amdgcn_perm(fbits(d0[j][1]), fbits(d0[j][0]), 0x07060302u);
        s0f.u[1] = __builtin_amdgcn_perm(fbits(d0[j][3]), fbits(d0[j][2]), 0x07060302u);
        s0f.u[2] = __builtin_amdgcn_perm(fbits(d1[j][1]), fbits(d1[j][0]), 0x07060302u);
        s0f.u[3] = __builtin_amdgcn_perm(fbits(d1[j][3]), fbits(d1[j][2]), 0x07060302u);
        s1f.u[0] = __builtin_amdgcn_perm(fbits(d2[j][1]), fbits(d2[j][0]), 0x07060302u);
        s1f.u[1] = __builtin_amdgcn_perm(fbits(d2[j][3]), fbits(d2[j][2]), 0x07060302u);
        s1f.u[2] = __builtin_amdgcn_perm(fbits(d3[j][1]), fbits(d3[j][0]), 0x07060302u);
        s1f.u[3] = __builtin_amdgcn_perm(fbits(d3[j][3]), fbits(d3[j][2]), 0x07060302u);

        // GEMM1: D1[hidden][cell], bias in C
        f32x4 acc = F.b1v;
        acc = __builtin_amdgcn_mfma_f32_16x16x32_bf16(F.w1h0, s0f.v, acc, 0, 0, 0);
        acc = __builtin_amdgcn_mfma_f32_16x16x32_bf16(F.w1l0, s0f.v, acc, 0, 0, 0);
        acc = __builtin_amdgcn_mfma_f32_16x16x32_bf16(F.w1h1, s1f.v, acc, 0, 0, 0);
        acc = __builtin_amdgcn_mfma_f32_16x16x32_bf16(F.w1l1, s1f.v, acc, 0, 0, 0);

        // tanh -> h[4q+r][col]
        float h0t, h1t, h2t, h3t;
        {
            float e;
            e = __expf(2.0f * acc[0]); h0t = 1.0f - 2.0f * __builtin_amdgcn_rcpf(e + 1.0f);
            e = __expf(2.0f * acc[1]); h1t = 1.0f - 2.0f * __builtin_amdgcn_rcpf(e + 1.0f);
            e = __expf(2.0f * acc[2]); h2t = 1.0f - 2.0f * __builtin_amdgcn_rcpf(e + 1.0f);
            e = __expf(2.0f * acc[3]); h3t = 1.0f - 2.0f * __builtin_amdgcn_rcpf(e + 1.0f);
        }
        union { bf16x8 v; unsigned int u[4]; } hf;
        hf.u[0] = pack_bf16_rne(h0t, h1t);
        hf.u[1] = pack_bf16_rne(h2t, h3t);
        hf.u[2] = 0u;
        hf.u[3] = 0u;

        // GEMM2: D2[s][cell], bias in C
        f32x4 acc2 = F.b2v;
        acc2 = __builtin_amdgcn_mfma_f32_16x16x32_bf16(F.w2h, hf.v, acc2, 0, 0, 0);
        acc2 = __builtin_amdgcn_mfma_f32_16x16x32_bf16(F.w2l, hf.v, acc2, 0, 0, 0);

        if (quad < 2) {
            *(f32x4*)(out + (size_t)((t0 + j) * 16 + col) * 8 + quad * 4) = acc2;
        }
    }
}

extern "C" void kernel_launch(void* const* d_in, const int* in_sizes, int n_in,
                              void* d_out, int out_size, void* d_ws, size_t ws_size,
                              hipStream_t stream) {
    const float* states = (const float*)d_in[0];
    const float* W1     = (const float*)d_in[1];
    const float* b1     = (const float*)d_in[2];
    const float* W2     = (const float*)d_in[3];
    const float* b2     = (const float*)d_in[4];
    float* out          = (float*)d_out;

    const bool use_ws = ws_size >= (size_t)(8 * 64 * 16);
    if (use_ws) {
        hipLaunchKernelGGL(setup_kernel, dim3(1), dim3(64), 0, stream,
                           W1, b1, W2, b2, (u32x4*)d_ws);
        hipLaunchKernelGGL((lattice_kernel<true>), dim3(8192), dim3(256), 0, stream,
                           states, W1, b1, W2, b2, out, (const u32x4*)d_ws);
    } else {
        hipLaunchKernelGGL((lattice_kernel<false>), dim3(8192), dim3(256), 0, stream,
                           states, W1, b1, W2, b2, out, (const u32x4*)d_ws);
    }
}

// Round 5
// 133.632 us; speedup vs baseline: 1.1685x; 1.0766x over previous
//
#include <hip/hip_runtime.h>

#define DIM 128

typedef __attribute__((ext_vector_type(8))) short bf16x8;
typedef __attribute__((ext_vector_type(4))) float f32x4;
typedef __attribute__((ext_vector_type(4))) unsigned int u32x4;

static __device__ __forceinline__ unsigned short f2bf_rne(float f) {
    union { float f; unsigned int i; } c; c.f = f;
    unsigned int u = c.i;
    return (unsigned short)((u + 0x7fffu + ((u >> 16) & 1u)) >> 16);
}
static __device__ __forceinline__ float bf2f(unsigned short u) {
    union { unsigned int i; float f; } c; c.i = ((unsigned int)u) << 16;
    return c.f;
}
static __device__ __forceinline__ unsigned int fbits(float f) {
    union { float f; unsigned int i; } c; c.f = f; return c.i;
}
static __device__ __forceinline__ unsigned int pack_bf16_rne(float lo, float hi) {
    unsigned int ul = fbits(lo), uh = fbits(hi);
    unsigned int tl = ul + 0x7fffu + ((ul >> 16) & 1u);
    unsigned int th = uh + 0x7fffu + ((uh >> 16) & 1u);
    return __builtin_amdgcn_perm(th, tl, 0x07060302u);
}

struct Frags {
    bf16x8 w1h0, w1l0, w1h1, w1l1, w2h, w2l;
    f32x4 b1v, b2v;
};

// A = W1^T (hi/lo bf16 split), A2 = W2 embed (hi/lo). k-order of W1 rows:
// [own 0..7 | x-1 | x+1 | y-1 | y+1 | z-1 | z+1] -> block0 quads {own,x-1,x+1,y-1},
// block1 quads {y+1,z-1,z+1,pad(zero weights)}.
static __device__ __forceinline__ void build_frags(
    const float* W1, const float* b1, const float* W2, const float* b2,
    int col, int quad, Frags& F)
{
#pragma unroll
    for (int j = 0; j < 8; ++j) {
        int k0 = quad * 8 + j;
        float w = W1[k0 * 16 + col];
        unsigned short hi = f2bf_rne(w);
        F.w1h0[j] = (short)hi;
        F.w1l0[j] = (short)f2bf_rne(w - bf2f(hi));

        int k1 = 32 + quad * 8 + j;
        float wv = (k1 < 56) ? W1[k1 * 16 + col] : 0.0f;
        hi = f2bf_rne(wv);
        F.w1h1[j] = (short)hi;
        F.w1l1[j] = (short)f2bf_rne(wv - bf2f(hi));

        float w2 = (j < 4 && col < 8) ? W2[(quad * 4 + j) * 8 + col] : 0.0f;
        hi = f2bf_rne(w2);
        F.w2h[j] = (short)hi;
        F.w2l[j] = (short)f2bf_rne(w2 - bf2f(hi));
    }
#pragma unroll
    for (int r = 0; r < 4; ++r) {
        F.b1v[r] = b1[quad * 4 + r];
        F.b2v[r] = (quad < 2) ? b2[quad * 4 + r] : 0.0f;
    }
}

__global__ __launch_bounds__(64) void setup_kernel(
    const float* __restrict__ W1, const float* __restrict__ b1,
    const float* __restrict__ W2, const float* __restrict__ b2,
    u32x4* __restrict__ ws)
{
    const int lane = threadIdx.x;
    Frags F;
    build_frags(W1, b1, W2, b2, lane & 15, lane >> 4, F);
    union { bf16x8 v; u32x4 u; } c;
    c.v = F.w1h0; ws[0 * 64 + lane] = c.u;
    c.v = F.w1l0; ws[1 * 64 + lane] = c.u;
    c.v = F.w1h1; ws[2 * 64 + lane] = c.u;
    c.v = F.w1l1; ws[3 * 64 + lane] = c.u;
    c.v = F.w2h;  ws[4 * 64 + lane] = c.u;
    c.v = F.w2l;  ws[5 * 64 + lane] = c.u;
    union { f32x4 v; u32x4 u; } b;
    b.v = F.b1v; ws[6 * 64 + lane] = b.u;
    b.v = F.b2v; ws[7 * 64 + lane] = b.u;
}

// Block (256 thr = 4 waves) covers x=0..127, y=y0..y0+3, one z.
// Stage 14 rows (4 KB each) into LDS with lane-linear 1 KB loads (TA fast path),
// barrier once, then wave w computes row y0+w (8 tiles of 16 cells) from LDS.
// Rows in LDS: r=0..5 -> (y0-1+r, z); r=6..9 -> (y0+r-6, z-1); r=10..13 -> (y0+r-10, z+1).
template<bool USE_WS>
__global__ __launch_bounds__(256, 2) void lattice_kernel(
    const float* __restrict__ states,
    const float* __restrict__ W1, const float* __restrict__ b1,
    const float* __restrict__ W2, const float* __restrict__ b2,
    float* __restrict__ out, const u32x4* __restrict__ ws)
{
    __shared__ __align__(16) float rows[14 * 1024];   // 57344 B

    const int tid  = threadIdx.x;
    const int lane = tid & 63;
    const int wave = tid >> 6;
    const int col  = lane & 15;
    const int quad = lane >> 4;

    Frags F;
    if (USE_WS) {
        union { u32x4 u; bf16x8 v; } c;
        c.u = ws[0 * 64 + lane]; F.w1h0 = c.v;
        c.u = ws[1 * 64 + lane]; F.w1l0 = c.v;
        c.u = ws[2 * 64 + lane]; F.w1h1 = c.v;
        c.u = ws[3 * 64 + lane]; F.w1l1 = c.v;
        c.u = ws[4 * 64 + lane]; F.w2h  = c.v;
        c.u = ws[5 * 64 + lane]; F.w2l  = c.v;
        union { u32x4 u; f32x4 v; } b;
        b.u = ws[6 * 64 + lane]; F.b1v = b.v;
        b.u = ws[7 * 64 + lane]; F.b2v = b.v;
    } else {
        build_frags(W1, b1, W2, b2, col, quad, F);
    }

    // z-slab XCD swizzle: blockIdx&7 -> 16-z-plane slab
    const int bI   = blockIdx.x;
    const int slab = bI & 7;
    const int inr  = bI >> 3;            // 0..511
    const int z    = slab * 16 + (inr >> 5);
    const int y0   = (inr & 31) << 2;

    // ---- stage 14 rows: 56 lane-linear 1 KB chunks; wave w does chunks w*14..w*14+13 ----
    f32x4 tmp[14];
#pragma unroll
    for (int i = 0; i < 14; ++i) {
        const int c  = wave * 14 + i;
        const int r  = c >> 2;           // row 0..13
        const int p  = c & 3;            // 1 KB part
        int yr, zr;
        if (r < 6)       { yr = (y0 - 1 + r) & 127; zr = z; }
        else if (r < 10) { yr = y0 + (r - 6);       zr = (z - 1) & 127; }
        else             { yr = y0 + (r - 10);      zr = (z + 1) & 127; }
        const float* g = states + (size_t)(zr * 16384 + yr * 128) * 8 + p * 256 + (lane << 2);
        tmp[i] = *(const f32x4*)g;
    }
#pragma unroll
    for (int i = 0; i < 14; ++i) {
        const int c = wave * 14 + i;
        const int r = c >> 2;
        const int p = c & 3;
        *(f32x4*)(&rows[r * 1024 + p * 256 + (lane << 2)]) = tmp[i];
    }
    __syncthreads();

    // ---- per-lane LDS row selectors ----
    const int rA  = (quad == 3) ? wave : wave + 1;                 // block0: own/own/own/y-1
    const int dxA = (quad == 1) ? -1 : (quad == 2) ? 1 : 0;        // x-shift for x+-1 quads
    const int rB  = (quad == 1) ? 6 + wave : (quad == 2) ? 10 + wave : wave + 2;  // y+1/z-1/z+1/pad

    const int outrow = z * 16384 + (y0 + wave) * 128;

#pragma unroll
    for (int i = 0; i < 8; ++i) {
        const int X  = i << 4;
        const int xA = (X + col + dxA) & 127;
        const float* pA = &rows[rA * 1024 + xA * 8];
        f32x4 a0 = *(const f32x4*)pA;
        f32x4 a1 = *(const f32x4*)(pA + 4);
        const float* pB = &rows[rB * 1024 + (X + col) * 8];
        f32x4 c0 = *(const f32x4*)pB;
        f32x4 c1 = *(const f32x4*)(pB + 4);

        union { bf16x8 v; unsigned int u[4]; } s0f, s1f;
        s0f.u[0] = __builtin_amdgcn_perm(fbits(a0[1]), fbits(a0[0]), 0x07060302u);
        s0f.u[1] = __builtin_amdgcn_perm(fbits(a0[3]), fbits(a0[2]), 0x07060302u);
        s0f.u[2] = __builtin_amdgcn_perm(fbits(a1[1]), fbits(a1[0]), 0x07060302u);
        s0f.u[3] = __builtin_amdgcn_perm(fbits(a1[3]), fbits(a1[2]), 0x07060302u);
        s1f.u[0] = __builtin_amdgcn_perm(fbits(c0[1]), fbits(c0[0]), 0x07060302u);
        s1f.u[1] = __builtin_amdgcn_perm(fbits(c0[3]), fbits(c0[2]), 0x07060302u);
        s1f.u[2] = __builtin_amdgcn_perm(fbits(c1[1]), fbits(c1[0]), 0x07060302u);
        s1f.u[3] = __builtin_amdgcn_perm(fbits(c1[3]), fbits(c1[2]), 0x07060302u);

        // GEMM1: D1[hidden][cell], bias in C
        f32x4 acc = F.b1v;
        acc = __builtin_amdgcn_mfma_f32_16x16x32_bf16(F.w1h0, s0f.v, acc, 0, 0, 0);
        acc = __builtin_amdgcn_mfma_f32_16x16x32_bf16(F.w1l0, s0f.v, acc, 0, 0, 0);
        acc = __builtin_amdgcn_mfma_f32_16x16x32_bf16(F.w1h1, s1f.v, acc, 0, 0, 0);
        acc = __builtin_amdgcn_mfma_f32_16x16x32_bf16(F.w1l1, s1f.v, acc, 0, 0, 0);

        // tanh
        float h0t, h1t, h2t, h3t;
        {
            float e;
            e = __expf(2.0f * acc[0]); h0t = 1.0f - 2.0f * __builtin_amdgcn_rcpf(e + 1.0f);
            e = __expf(2.0f * acc[1]); h1t = 1.0f - 2.0f * __builtin_amdgcn_rcpf(e + 1.0f);
            e = __expf(2.0f * acc[2]); h2t = 1.0f - 2.0f * __builtin_amdgcn_rcpf(e + 1.0f);
            e = __expf(2.0f * acc[3]); h3t = 1.0f - 2.0f * __builtin_amdgcn_rcpf(e + 1.0f);
        }
        union { bf16x8 v; unsigned int u[4]; } hf;
        hf.u[0] = pack_bf16_rne(h0t, h1t);
        hf.u[1] = pack_bf16_rne(h2t, h3t);
        hf.u[2] = 0u;
        hf.u[3] = 0u;

        // GEMM2: D2[s][cell], bias in C
        f32x4 acc2 = F.b2v;
        acc2 = __builtin_amdgcn_mfma_f32_16x16x32_bf16(F.w2h, hf.v, acc2, 0, 0, 0);
        acc2 = __builtin_amdgcn_mfma_f32_16x16x32_bf16(F.w2l, hf.v, acc2, 0, 0, 0);

        // store: lanes 0..31 contiguous 512 B (cell=col, s-half=quad)
        if (quad < 2) {
            *(f32x4*)(out + (size_t)(outrow + X + col) * 8 + quad * 4) = acc2;
        }
    }
}

extern "C" void kernel_launch(void* const* d_in, const int* in_sizes, int n_in,
                              void* d_out, int out_size, void* d_ws, size_t ws_size,
                              hipStream_t stream) {
    const float* states = (const float*)d_in[0];
    const float* W1     = (const float*)d_in[1];
    const float* b1     = (const float*)d_in[2];
    const float* W2     = (const float*)d_in[3];
    const float* b2     = (const float*)d_in[4];
    float* out          = (float*)d_out;

    const bool use_ws = ws_size >= (size_t)(8 * 64 * 16);
    if (use_ws) {
        hipLaunchKernelGGL(setup_kernel, dim3(1), dim3(64), 0, stream,
                           W1, b1, W2, b2, (u32x4*)d_ws);
        hipLaunchKernelGGL((lattice_kernel<true>), dim3(4096), dim3(256), 0, stream,
                           states, W1, b1, W2, b2, out, (const u32x4*)d_ws);
    } else {
        hipLaunchKernelGGL((lattice_kernel<false>), dim3(4096), dim3(256), 0, stream,
                           states, W1, b1, W2, b2, out, (const u32x4*)d_ws);
    }
}